// Round 15
// baseline (61.980 us; speedup 1.0000x reference)
//
#include <hip/hip_runtime.h>
#include <hip/hip_bf16.h>
#include <math.h>

// ---------------------------------------------------------------------------
// ActorNetwork, round 15: r14 + grid-stride mega (512 blocks x 2 groups).
//
// Exact algebraic folds: W_cq/W_ck dead; score via wQK = W_q^T W_k; W_v folded
// into mo weights via WCVV = W_cv @ W_v; W_fold = blockdiag fold of W_mo,W_cv.
//
// Theory ledger: r10 shfl-latency NULL; r11 barriers NULL; r12 depth-1 s2
// prefetch WIN; r13 depth-2 regress; r14 prelude merge WIN (36.1us).
// Round-15 single change: mega grid 1024 -> 512 blocks x 2 element-groups.
// At 3 blocks/CU (768 slots), 1024 blocks ran 768+256 two-round with a
// 1-block/CU tail (~25% of work at ~half efficiency); 512 blocks fit in ONE
// round. Phase-2 weight frags hoisted, loaded once per block. Barrier-safety
// audited: group-1 pre-barrier writes (xbL/TR) are sealed from group-0's
// phase-3a xbL reads by the "mo complete" barrier. unroll 1 on group loop.
// ---------------------------------------------------------------------------

typedef __attribute__((ext_vector_type(8))) short short8;
typedef __attribute__((ext_vector_type(4))) float f32x4;

// ws layout (4-byte units)
#define WS_A1F   0        // [4][256]  bf16 A-frags W_s1 (K=16 padded to 32)
#define WS_A2F   1024     // [8][256]  bf16 A-frags W_s2
#define WS_AOWN  3072     // [4][256]  bf16 A-frags W_own (K=16 padded to 32)
#define WS_AENV  4096     // [8][256]  bf16 A-frags W_env
#define WS_AQK   6144     // [8][256]  bf16 A-frags wQK^T
#define WS_FOLDF 8192     // [48][256] bf16 A-frags W_fold (h2 block x W_v)
#define WS_A1FR  20480    // [16][256] bf16 A-frags W_a1
#define WS_SETUP_END 24576
#define WS_WCVV  24576    // [64][64] f32  W_cv @ W_v

static __device__ inline unsigned pk2(float a, float b) {
    union { __hip_bfloat162 h; unsigned u; } cv;
    cv.h = __float22bfloat162_rn(make_float2(a, b));
    return cv.u;
}

// Sum x over the four 16-lane rows, broadcast (VALU permlane swaps).
static __device__ inline float rowquad_sum(float x) {
    float a = x, b = x;
    asm("v_permlane16_swap_b32 %0, %1" : "+v"(a), "+v"(b));
    float y = a + b;
    float c = y, d = y;
    asm("v_permlane32_swap_b32 %0, %1" : "+v"(c), "+v"(d));
    return c + d;
}

// ------------------ K0a: merged WCVV (k-split x8) + pure-pack frags
__global__ void actor_prep1(
    const float* __restrict__ wCv,  const float* __restrict__ wV,
    const float* __restrict__ wOwn, const float* __restrict__ wEnv,
    const float* __restrict__ wS1,  const float* __restrict__ wS2,
    const float* __restrict__ wA1,  float* __restrict__ ws)
{
    unsigned* wsu = reinterpret_cast<unsigned*>(ws);
    if (blockIdx.x < 128) {                // WCVV = Wcv@Wv
        int t = blockIdx.x * 256 + threadIdx.x;   // < 32768
        int out = t >> 3, sl = t & 7;
        int c = out >> 6, d = out & 63;
        float acc = 0.f;
        #pragma unroll
        for (int i = 0; i < 8; ++i) {
            int e = sl * 8 + i;
            acc = fmaf(wCv[c * 64 + e], wV[e * 64 + d], acc);
        }
        acc += __shfl_xor(acc, 1, 64);
        acc += __shfl_xor(acc, 2, 64);
        acc += __shfl_xor(acc, 4, 64);
        if (sl == 0) ws[WS_WCVV + out] = acc;
        return;
    }
    int t = (blockIdx.x - 128) * 256 + threadIdx.x;   // < 10240
    if (t < 1024) {                        // A1F: W_s1 rows, ZERO-padded k>=16
        int ht = t >> 8, rem = t & 255, lane = rem >> 2, jj = rem & 3;
        int qq = lane >> 4, m = lane & 15;
        int row = ht * 16 + m, k0 = qq * 8 + jj * 2;
        float v0 = (k0 < 16) ? wS1[row * 16 + k0]     : 0.f;
        float v1 = (k0 < 16) ? wS1[row * 16 + k0 + 1] : 0.f;
        wsu[WS_A1F + t] = pk2(v0, v1);
    } else if (t < 3072) {                 // A2F: W_s2 frags
        int u = t - 1024;
        int f = u >> 8, rem = u & 255, lane = rem >> 2, jj = rem & 3;
        int qq = lane >> 4, m = lane & 15;
        int dt = f >> 1, kt = f & 1;
        int row = dt * 16 + m, k = kt * 32 + qq * 8 + jj * 2;
        wsu[WS_A2F + u] = pk2(wS2[row * 64 + k], wS2[row * 64 + k + 1]);
    } else if (t < 4096) {                 // AOWN: W_own rows, ZERO-padded k>=16
        int u = t - 3072;
        int ht = u >> 8, rem = u & 255, lane = rem >> 2, jj = rem & 3;
        int qq = lane >> 4, m = lane & 15;
        int row = ht * 16 + m, k0 = qq * 8 + jj * 2;
        float v0 = (k0 < 16) ? wOwn[row * 16 + k0]     : 0.f;
        float v1 = (k0 < 16) ? wOwn[row * 16 + k0 + 1] : 0.f;
        wsu[WS_AOWN + u] = pk2(v0, v1);
    } else if (t < 6144) {                 // AENV: W_env frags
        int u = t - 4096;
        int f = u >> 8, rem = u & 255, lane = rem >> 2, jj = rem & 3;
        int qq = lane >> 4, m = lane & 15;
        int ht = f >> 1, kt = f & 1;
        int row = ht * 16 + m, k = kt * 32 + qq * 8 + jj * 2;
        wsu[WS_AENV + u] = pk2(wEnv[row * 64 + k], wEnv[row * 64 + k + 1]);
    } else {                               // A1FR: W_a1 frags (t < 10240)
        int u = t - 6144;
        int f = u >> 8, rem = u & 255, lane = rem >> 2, jj = rem & 3;
        int rt = f >> 2, kt = f & 3;
        int row = rt * 16 + (lane & 15);
        int k = kt * 32 + (lane >> 4) * 8 + jj * 2;
        wsu[WS_A1FR + u] = pk2(wA1[row * 128 + k], wA1[row * 128 + k + 1]);
    }
}

// ------------------------------------- K0c: FOLDF + AQK (k-split x8)
__global__ void actor_setup_gemm(
    const float* __restrict__ wQ,  const float* __restrict__ wK,
    const float* __restrict__ wCv, const float* __restrict__ wMo,
    float* __restrict__ ws)
{
    int t = blockIdx.x * 256 + threadIdx.x;   // < 114688
    unsigned* wsu = reinterpret_cast<unsigned*>(ws);
    if (t < 98304) {                       // FOLDF: 12288 outs x 8 slices
        int u = t >> 3, sl = t & 7;
        int f = u >> 8, rem = u & 255, lane = rem >> 2, jj = rem & 3;
        int RT = f / 6, kt = f - RT * 6;
        int row = RT * 16 + (lane & 15);
        int k = kt * 32 + (lane >> 4) * 8 + jj * 2;
        int h = k >> 6, dp = k & 63;
        const float* wmr = wMo + row * 192 + h * 64;
        const float* rhs = (h == 2) ? (ws + WS_WCVV) : wCv;   // WCVV = Wcv@Wv
        float a0 = 0.f, a1 = 0.f;
        #pragma unroll
        for (int i = 0; i < 8; ++i) {
            int d = sl * 8 + i;
            float m = wmr[d];
            a0 = fmaf(m, rhs[d * 64 + dp],     a0);
            a1 = fmaf(m, rhs[d * 64 + dp + 1], a1);
        }
        a0 += __shfl_xor(a0, 1, 64); a0 += __shfl_xor(a0, 2, 64); a0 += __shfl_xor(a0, 4, 64);
        a1 += __shfl_xor(a1, 1, 64); a1 += __shfl_xor(a1, 2, 64); a1 += __shfl_xor(a1, 4, 64);
        if (sl == 0) wsu[WS_FOLDF + u] = pk2(a0, a1);
    } else {                               // AQK: 2048 outs x 8 slices
        int v = t - 98304;
        int u = v >> 3, sl = v & 7;
        int f = u >> 8, rem = u & 255, lane = rem >> 2, jj = rem & 3;
        int qq = lane >> 4, m = lane & 15;
        int dt = f >> 1, kt = f & 1;
        int dp = dt * 16 + m;
        int e = kt * 32 + qq * 8 + jj * 2;
        float a0 = 0.f, a1 = 0.f;
        #pragma unroll
        for (int i = 0; i < 8; ++i) {
            int d = sl * 8 + i;
            float kd = wK[d * 64 + dp];
            a0 = fmaf(wQ[d * 64 + e],     kd, a0);
            a1 = fmaf(wQ[d * 64 + e + 1], kd, a1);
        }
        a0 += __shfl_xor(a0, 1, 64); a0 += __shfl_xor(a0, 2, 64); a0 += __shfl_xor(a0, 4, 64);
        a1 += __shfl_xor(a1, 1, 64); a1 += __shfl_xor(a1, 2, 64); a1 += __shfl_xor(a1, 4, 64);
        if (sl == 0) wsu[WS_AQK + u] = pk2(a0, a1);
    }
}

// ------------- K1: fused pipeline (r12 body; 512 blocks x 2 groups)
__global__ __launch_bounds__(256, 3) void actor_mega(
    const float* __restrict__ s0g, const float* __restrict__ s1g,
    const float* __restrict__ s2g,
    const float* __restrict__ bOwn, const float* __restrict__ bEnv,
    const float* __restrict__ bS1g, const float* __restrict__ bS2g,
    const float* __restrict__ bMo,  const float* __restrict__ bA1,
    const float* __restrict__ wA2,  const float* __restrict__ bA2,
    const float* __restrict__ ws,   float* __restrict__ outg)
{
    __shared__ char   xbL[16 * 384];
    __shared__ float  qkL[16][72];          // fp32 qk rows
    __shared__ ushort Hl[4][2][16 * 72];    // per-wave H double-buffer
    __shared__ ushort TR[16 * 72];          // own_e^T staging for qk B-frag
    __shared__ char   mbL[16 * 256];        // mo rows bf16, swizzled
    __shared__ float  aL[16][66];           // a rows fp32

    const int tid  = threadIdx.x;
    const int wid  = tid >> 6;
    const int lane = tid & 63;
    const int q    = lane >> 4;
    const int r    = lane & 15;
    const int swzr = (r & 7) << 4;
    const f32x4 z = {0.f, 0.f, 0.f, 0.f};

    // hoisted phase-2 weight frags: loaded ONCE per block (amortized 2 groups)
    short8 A1[4], A2[8];
    {
        const short8* p1 = reinterpret_cast<const short8*>(ws + WS_A1F);
        #pragma unroll
        for (int ht = 0; ht < 4; ++ht) A1[ht] = p1[ht * 64 + lane];
        const short8* p2 = reinterpret_cast<const short8*>(ws + WS_A2F);
        #pragma unroll
        for (int f = 0; f < 8; ++f) A2[f] = p2[f * 64 + lane];
    }
    f32x4 b1c[4], b2c[4];
    #pragma unroll
    for (int t4 = 0; t4 < 4; ++t4) {
        b1c[t4] = *reinterpret_cast<const f32x4*>(bS1g + t4 * 16 + q * 4);
        b2c[t4] = *reinterpret_cast<const f32x4*>(bS2g + t4 * 16 + q * 4);
    }

    #pragma unroll 1
    for (int grp = 0; grp < 2; ++grp) {
        const int eb = blockIdx.x * 32 + grp * 16;

        // ---------------- Phase 1a: own_e (wave wid -> feature tile ht=wid)
        {
            short8 Ao = reinterpret_cast<const short8*>(ws + WS_AOWN)[wid * 64 + lane];
            const float* sp = s0g + (size_t)(eb + r) * 16 + (q & 1) * 8;
            float4 sa = *reinterpret_cast<const float4*>(sp);
            float4 sb = *reinterpret_cast<const float4*>(sp + 4);
            union { short8 s8; unsigned u[4]; } B;
            B.u[0] = pk2(sa.x, sa.y); B.u[1] = pk2(sa.z, sa.w);
            B.u[2] = pk2(sb.x, sb.y); B.u[3] = pk2(sb.z, sb.w);
            f32x4 c = *reinterpret_cast<const f32x4*>(bOwn + wid * 16 + q * 4);
            f32x4 D = __builtin_amdgcn_mfma_f32_16x16x32_bf16(Ao, B.s8, c, 0, 0, 0);
            unsigned p0 = pk2(fmaxf(D[0], 0.f), fmaxf(D[1], 0.f));
            unsigned p1 = pk2(fmaxf(D[2], 0.f), fmaxf(D[3], 0.f));
            *reinterpret_cast<uint2*>(xbL + r * 384 + ((wid * 32 + q * 8) ^ swzr)) =
                make_uint2(p0, p1);
            *reinterpret_cast<uint2*>(reinterpret_cast<char*>(TR) + r * 144 + wid * 32 + q * 8) =
                make_uint2(p0, p1);
        }
        // ---------------- Phase 1b: env_e
        {
            short8 Ae0 = reinterpret_cast<const short8*>(ws + WS_AENV)[(wid * 2 + 0) * 64 + lane];
            short8 Ae1 = reinterpret_cast<const short8*>(ws + WS_AENV)[(wid * 2 + 1) * 64 + lane];
            const float* sb1 = s1g + (size_t)(eb + r) * 64;
            f32x4 D = *reinterpret_cast<const f32x4*>(bEnv + wid * 16 + q * 4);
            {
                float4 sa = *reinterpret_cast<const float4*>(sb1 + q * 8);
                float4 sb = *reinterpret_cast<const float4*>(sb1 + q * 8 + 4);
                union { short8 s8; unsigned u[4]; } B;
                B.u[0] = pk2(sa.x, sa.y); B.u[1] = pk2(sa.z, sa.w);
                B.u[2] = pk2(sb.x, sb.y); B.u[3] = pk2(sb.z, sb.w);
                D = __builtin_amdgcn_mfma_f32_16x16x32_bf16(Ae0, B.s8, D, 0, 0, 0);
            }
            {
                float4 sa = *reinterpret_cast<const float4*>(sb1 + 32 + q * 8);
                float4 sb = *reinterpret_cast<const float4*>(sb1 + 32 + q * 8 + 4);
                union { short8 s8; unsigned u[4]; } B;
                B.u[0] = pk2(sa.x, sa.y); B.u[1] = pk2(sa.z, sa.w);
                B.u[2] = pk2(sb.x, sb.y); B.u[3] = pk2(sb.z, sb.w);
                D = __builtin_amdgcn_mfma_f32_16x16x32_bf16(Ae1, B.s8, D, 0, 0, 0);
            }
            unsigned p0 = pk2(fmaxf(D[0], 0.f), fmaxf(D[1], 0.f));
            unsigned p1 = pk2(fmaxf(D[2], 0.f), fmaxf(D[3], 0.f));
            *reinterpret_cast<uint2*>(xbL + r * 384 + ((128 + wid * 32 + q * 8) ^ swzr)) =
                make_uint2(p0, p1);
        }
        __syncthreads();   // TR complete

        // ---------------- Phase 1c: qk = own_e @ wQK
        {
            short8 Aq0 = reinterpret_cast<const short8*>(ws + WS_AQK)[(wid * 2 + 0) * 64 + lane];
            short8 Aq1 = reinterpret_cast<const short8*>(ws + WS_AQK)[(wid * 2 + 1) * 64 + lane];
            const char* trb = reinterpret_cast<const char*>(TR) + r * 144;
            short8 B0 = *reinterpret_cast<const short8*>(trb + q * 16);
            short8 B1 = *reinterpret_cast<const short8*>(trb + 64 + q * 16);
            f32x4 D = __builtin_amdgcn_mfma_f32_16x16x32_bf16(Aq0, B0, z, 0, 0, 0);
            D = __builtin_amdgcn_mfma_f32_16x16x32_bf16(Aq1, B1, D, 0, 0, 0);
            *reinterpret_cast<f32x4*>(&qkL[r][wid * 16 + q * 4]) = D;
        }
        __syncthreads();   // qkL complete

        // ---------------- Phase 2: neighbor loop
        const int el   = r >> 2;
        const int j    = r & 3;
        const int sloc = wid * 4 + el;

        float qkf[16];
        #pragma unroll
        for (int dt = 0; dt < 4; ++dt) {
            f32x4 v = *reinterpret_cast<const f32x4*>(&qkL[sloc][dt * 16 + q * 4]);
            qkf[dt*4+0] = v[0]; qkf[dt*4+1] = v[1]; qkf[dt*4+2] = v[2]; qkf[dt*4+3] = v[3];
        }
        const float* s2base = s2g + (size_t)(eb + sloc) * 512 + (q & 1) * 8;

        float den = 0.f;
        f32x4 Pac[4] = {{0,0,0,0},{0,0,0,0},{0,0,0,0},{0,0,0,0}};

        float4 pfa = *reinterpret_cast<const float4*>(s2base + j * 16);
        float4 pfb = *reinterpret_cast<const float4*>(s2base + j * 16 + 4);

        #pragma unroll 2
        for (int it = 0; it < 8; ++it) {
            float4 sa = pfa, sb = pfb;
            if (it < 7) {
                const float* sp = s2base + ((it + 1) * 4 + j) * 16;
                pfa = *reinterpret_cast<const float4*>(sp);
                pfb = *reinterpret_cast<const float4*>(sp + 4);
            }
            union { short8 s8; unsigned u[4]; } B1;
            B1.u[0] = pk2(sa.x, sa.y); B1.u[1] = pk2(sa.z, sa.w);
            B1.u[2] = pk2(sb.x, sb.y); B1.u[3] = pk2(sb.z, sb.w);

            f32x4 hD[4];
            #pragma unroll
            for (int ht = 0; ht < 4; ++ht)
                hD[ht] = __builtin_amdgcn_mfma_f32_16x16x32_bf16(A1[ht], B1.s8, b1c[ht], 0, 0, 0);

            ushort* hrow = &Hl[wid][it & 1][r * 72];
            #pragma unroll
            for (int ht = 0; ht < 4; ++ht) {
                float h0 = fmaxf(hD[ht][0], 0.f), h1 = fmaxf(hD[ht][1], 0.f);
                float h2 = fmaxf(hD[ht][2], 0.f), h3 = fmaxf(hD[ht][3], 0.f);
                *reinterpret_cast<uint2*>(hrow + ht * 16 + q * 4) =
                    make_uint2(pk2(h0, h1), pk2(h2, h3));
            }
            short8 B2a = *reinterpret_cast<const short8*>(hrow + q * 8);
            short8 B2b = *reinterpret_cast<const short8*>(hrow + 32 + q * 8);

            f32x4 iD[4];
            #pragma unroll
            for (int dt = 0; dt < 4; ++dt) {
                f32x4 c0 = __builtin_amdgcn_mfma_f32_16x16x32_bf16(A2[dt*2+0], B2a, b2c[dt], 0, 0, 0);
                iD[dt]   = __builtin_amdgcn_mfma_f32_16x16x32_bf16(A2[dt*2+1], B2b, c0, 0, 0, 0);
            }
            float rs = 0.f, sc = 0.f;
            #pragma unroll
            for (int dt = 0; dt < 4; ++dt) {
                #pragma unroll
                for (int i = 0; i < 4; ++i) {
                    float x = fmaxf(iD[dt][i], 0.f);
                    iD[dt][i] = x;
                    rs += x;
                    sc = fmaf(x, qkf[dt*4+i], sc);
                }
            }
            sc = rowquad_sum(sc);
            rs = rowquad_sum(rs);
            float w = (rs != 0.f) ? __expf(sc * 0.125f) : 0.f;  // scores O(1e-2)
            den += w;
            #pragma unroll
            for (int dt = 0; dt < 4; ++dt)
                #pragma unroll
                for (int i = 0; i < 4; ++i)
                    Pac[dt][i] = fmaf(w, iD[dt][i], Pac[dt][i]);
        }
        #pragma unroll
        for (int m = 1; m <= 2; m <<= 1) {
            den += __shfl_xor(den, m, 64);
            #pragma unroll
            for (int dt = 0; dt < 4; ++dt)
                #pragma unroll
                for (int i = 0; i < 4; ++i)
                    Pac[dt][i] += __shfl_xor(Pac[dt][i], m, 64);
        }
        {
            float inv = (den > 0.f) ? (1.f / den) : 0.f;   // all-masked -> P = 0
            if (j == 0) {
                const int swzs = (sloc & 7) << 4;
                #pragma unroll
                for (int dt = 0; dt < 4; ++dt) {
                    float p0 = Pac[dt][0] * inv, p1 = Pac[dt][1] * inv;
                    float p2 = Pac[dt][2] * inv, p3 = Pac[dt][3] * inv;
                    *reinterpret_cast<uint2*>(xbL + sloc * 384 + ((256 + dt * 32 + q * 8) ^ swzs)) =
                        make_uint2(pk2(p0, p1), pk2(p2, p3));
                }
            }
        }
        __syncthreads();   // X tile complete

        // ---------------- Phase 3a: mo = X @ W_fold^T + b_mo
        {
            const short8* fp = reinterpret_cast<const short8*>(ws + WS_FOLDF);
            short8 Amo0[6], Amo1[6];
            #pragma unroll
            for (int kt = 0; kt < 6; ++kt) {
                Amo0[kt] = fp[((wid * 2 + 0) * 6 + kt) * 64 + lane];
                Amo1[kt] = fp[((wid * 2 + 1) * 6 + kt) * 64 + lane];
            }
            short8 Bf[6];
            #pragma unroll
            for (int kt = 0; kt < 6; ++kt)
                Bf[kt] = *reinterpret_cast<const short8*>(
                    xbL + r * 384 + ((kt * 64 + q * 16) ^ swzr));
            f32x4 D0 = z, D1 = z;
            #pragma unroll
            for (int kt = 0; kt < 6; ++kt) {
                D0 = __builtin_amdgcn_mfma_f32_16x16x32_bf16(Amo0[kt], Bf[kt], D0, 0, 0, 0);
                D1 = __builtin_amdgcn_mfma_f32_16x16x32_bf16(Amo1[kt], Bf[kt], D1, 0, 0, 0);
            }
            f32x4 bm0 = *reinterpret_cast<const f32x4*>(bMo + wid * 32 + q * 4);
            f32x4 bm1 = *reinterpret_cast<const f32x4*>(bMo + wid * 32 + 16 + q * 4);
            char* wp0 = mbL + r * 256 + ((wid * 64 + q * 8) ^ swzr);
            *reinterpret_cast<unsigned*>(wp0)     = pk2(D0[0] + bm0[0], D0[1] + bm0[1]);
            *reinterpret_cast<unsigned*>(wp0 + 4) = pk2(D0[2] + bm0[2], D0[3] + bm0[3]);
            char* wp1 = mbL + r * 256 + ((wid * 64 + 32 + q * 8) ^ swzr);
            *reinterpret_cast<unsigned*>(wp1)     = pk2(D1[0] + bm1[0], D1[1] + bm1[1]);
            *reinterpret_cast<unsigned*>(wp1 + 4) = pk2(D1[2] + bm1[2], D1[3] + bm1[3]);
        }
        __syncthreads();   // mo tile complete

        // ---------------- Phase 3b: a = relu(mo @ W_a1^T + b_a1)
        {
            const short8* ap = reinterpret_cast<const short8*>(ws + WS_A1FR);
            f32x4 D = z;
            #pragma unroll
            for (int kt = 0; kt < 4; ++kt) {
                short8 Ak = ap[(wid * 4 + kt) * 64 + lane];
                short8 Bk = *reinterpret_cast<const short8*>(
                    mbL + r * 256 + ((kt * 64 + q * 16) ^ swzr));
                D = __builtin_amdgcn_mfma_f32_16x16x32_bf16(Ak, Bk, D, 0, 0, 0);
            }
            f32x4 ba = *reinterpret_cast<const f32x4*>(bA1 + wid * 16 + q * 4);
            float a0 = fmaxf(D[0] + ba[0], 0.f), a1v = fmaxf(D[1] + ba[1], 0.f);
            float a2v = fmaxf(D[2] + ba[2], 0.f), a3v = fmaxf(D[3] + ba[3], 0.f);
            *reinterpret_cast<float2*>(&aL[r][wid * 16 + q * 4])     = make_float2(a0, a1v);
            *reinterpret_cast<float2*>(&aL[r][wid * 16 + q * 4 + 2]) = make_float2(a2v, a3v);
        }
        __syncthreads();   // a tile complete

        // ---------------- Phase 3c: out = tanh(a @ W_a2^T + b_a2)
        if (tid < 32) {
            const int s = tid & 15, o = tid >> 4;
            const float* wr = wA2 + o * 64;
            float p = 0.f;
            #pragma unroll
            for (int d = 0; d < 64; ++d) p = fmaf(aL[s][d], wr[d], p);
            outg[(size_t)(eb + s) * 2 + o] = tanhf(p + bA2[o]);
        }
    }
}

extern "C" void kernel_launch(void* const* d_in, const int* in_sizes, int n_in,
                              void* d_out, int out_size, void* d_ws, size_t ws_size,
                              hipStream_t stream) {
    const float* s0   = (const float*)d_in[0];
    const float* s1   = (const float*)d_in[1];
    const float* s2   = (const float*)d_in[2];
    const float* wOwn = (const float*)d_in[3];
    const float* bOwn = (const float*)d_in[4];
    const float* wEnv = (const float*)d_in[5];
    const float* bEnv = (const float*)d_in[6];
    const float* wS1  = (const float*)d_in[7];
    const float* bS1  = (const float*)d_in[8];
    const float* wS2  = (const float*)d_in[9];
    const float* bS2  = (const float*)d_in[10];
    const float* wQ   = (const float*)d_in[11];
    const float* wK   = (const float*)d_in[12];
    const float* wV   = (const float*)d_in[13];
    // d_in[14] (W_cq) / d_in[15] (W_ck): dead code in the reference.
    const float* wCv  = (const float*)d_in[16];
    const float* wMo  = (const float*)d_in[17];
    const float* bMo  = (const float*)d_in[18];
    const float* wA1  = (const float*)d_in[19];
    const float* bA1  = (const float*)d_in[20];
    const float* wA2  = (const float*)d_in[21];
    const float* bA2  = (const float*)d_in[22];
    float* ws  = (float*)d_ws;
    float* out = (float*)d_out;

    hipLaunchKernelGGL(actor_prep1, dim3(168), dim3(256), 0, stream,
                       wCv, wV, wOwn, wEnv, wS1, wS2, wA1, ws);
    hipLaunchKernelGGL(actor_setup_gemm, dim3(448), dim3(256), 0, stream,
                       wQ, wK, wCv, wMo, ws);
    hipLaunchKernelGGL(actor_mega, dim3(16384 / 32), dim3(256), 0, stream,
                       s0, s1, s2, bOwn, bEnv, bS1, bS2, bMo, bA1, wA2, bA2,
                       ws, out);
}

// Round 16
// 36.078 us; speedup vs baseline: 1.7180x; 1.7180x over previous
//
#include <hip/hip_runtime.h>
#include <hip/hip_bf16.h>
#include <math.h>

// ---------------------------------------------------------------------------
// ActorNetwork, round 16: REVERT to round-14 artifact (best known: 36.1us).
//
// Exact algebraic folds: W_cq/W_ck dead; score via wQK = W_q^T W_k; W_v folded
// into mo weights via WCVV = W_cv @ W_v; W_fold = blockdiag fold of W_mo,W_cv.
//
// Final theory ledger: r12 depth-1 s2 prefetch WIN; r14 prelude merge WIN;
// r10 shfl-latency NULL; r11 barrier-free NULL; r13 depth-2 regress;
// r7/r8/r15 register-structure edits -> spill cliff (VGPR 64-84, 30-109MB
// scratch) THREE times. Codegen is bimodal; r14's shape is the clean mode.
// Remaining gap to ~9us compute+HBM floor is dep-chain latency at fixed
// 12 waves/CU; the only lever (4 blocks/CU via <=128 VGPR) is blocked.
// ---------------------------------------------------------------------------

typedef __attribute__((ext_vector_type(8))) short short8;
typedef __attribute__((ext_vector_type(4))) float f32x4;

// ws layout (4-byte units)
#define WS_A1F   0        // [4][256]  bf16 A-frags W_s1 (K=16 padded to 32)
#define WS_A2F   1024     // [8][256]  bf16 A-frags W_s2
#define WS_AOWN  3072     // [4][256]  bf16 A-frags W_own (K=16 padded to 32)
#define WS_AENV  4096     // [8][256]  bf16 A-frags W_env
#define WS_AQK   6144     // [8][256]  bf16 A-frags wQK^T
#define WS_FOLDF 8192     // [48][256] bf16 A-frags W_fold (h2 block x W_v)
#define WS_A1FR  20480    // [16][256] bf16 A-frags W_a1
#define WS_SETUP_END 24576
#define WS_WCVV  24576    // [64][64] f32  W_cv @ W_v

static __device__ inline unsigned pk2(float a, float b) {
    union { __hip_bfloat162 h; unsigned u; } cv;
    cv.h = __float22bfloat162_rn(make_float2(a, b));
    return cv.u;
}

// Sum x over the four 16-lane rows, broadcast (VALU permlane swaps).
static __device__ inline float rowquad_sum(float x) {
    float a = x, b = x;
    asm("v_permlane16_swap_b32 %0, %1" : "+v"(a), "+v"(b));
    float y = a + b;
    float c = y, d = y;
    asm("v_permlane32_swap_b32 %0, %1" : "+v"(c), "+v"(d));
    return c + d;
}

// ------------------ K0a: merged WCVV (k-split x8) + pure-pack frags
__global__ void actor_prep1(
    const float* __restrict__ wCv,  const float* __restrict__ wV,
    const float* __restrict__ wOwn, const float* __restrict__ wEnv,
    const float* __restrict__ wS1,  const float* __restrict__ wS2,
    const float* __restrict__ wA1,  float* __restrict__ ws)
{
    unsigned* wsu = reinterpret_cast<unsigned*>(ws);
    if (blockIdx.x < 128) {                // WCVV = Wcv@Wv
        int t = blockIdx.x * 256 + threadIdx.x;   // < 32768
        int out = t >> 3, sl = t & 7;
        int c = out >> 6, d = out & 63;
        float acc = 0.f;
        #pragma unroll
        for (int i = 0; i < 8; ++i) {
            int e = sl * 8 + i;
            acc = fmaf(wCv[c * 64 + e], wV[e * 64 + d], acc);
        }
        acc += __shfl_xor(acc, 1, 64);
        acc += __shfl_xor(acc, 2, 64);
        acc += __shfl_xor(acc, 4, 64);
        if (sl == 0) ws[WS_WCVV + out] = acc;
        return;
    }
    int t = (blockIdx.x - 128) * 256 + threadIdx.x;   // < 10240
    if (t < 1024) {                        // A1F: W_s1 rows, ZERO-padded k>=16
        int ht = t >> 8, rem = t & 255, lane = rem >> 2, jj = rem & 3;
        int qq = lane >> 4, m = lane & 15;
        int row = ht * 16 + m, k0 = qq * 8 + jj * 2;
        float v0 = (k0 < 16) ? wS1[row * 16 + k0]     : 0.f;
        float v1 = (k0 < 16) ? wS1[row * 16 + k0 + 1] : 0.f;
        wsu[WS_A1F + t] = pk2(v0, v1);
    } else if (t < 3072) {                 // A2F: W_s2 frags
        int u = t - 1024;
        int f = u >> 8, rem = u & 255, lane = rem >> 2, jj = rem & 3;
        int qq = lane >> 4, m = lane & 15;
        int dt = f >> 1, kt = f & 1;
        int row = dt * 16 + m, k = kt * 32 + qq * 8 + jj * 2;
        wsu[WS_A2F + u] = pk2(wS2[row * 64 + k], wS2[row * 64 + k + 1]);
    } else if (t < 4096) {                 // AOWN: W_own rows, ZERO-padded k>=16
        int u = t - 3072;
        int ht = u >> 8, rem = u & 255, lane = rem >> 2, jj = rem & 3;
        int qq = lane >> 4, m = lane & 15;
        int row = ht * 16 + m, k0 = qq * 8 + jj * 2;
        float v0 = (k0 < 16) ? wOwn[row * 16 + k0]     : 0.f;
        float v1 = (k0 < 16) ? wOwn[row * 16 + k0 + 1] : 0.f;
        wsu[WS_AOWN + u] = pk2(v0, v1);
    } else if (t < 6144) {                 // AENV: W_env frags
        int u = t - 4096;
        int f = u >> 8, rem = u & 255, lane = rem >> 2, jj = rem & 3;
        int qq = lane >> 4, m = lane & 15;
        int ht = f >> 1, kt = f & 1;
        int row = ht * 16 + m, k = kt * 32 + qq * 8 + jj * 2;
        wsu[WS_AENV + u] = pk2(wEnv[row * 64 + k], wEnv[row * 64 + k + 1]);
    } else {                               // A1FR: W_a1 frags (t < 10240)
        int u = t - 6144;
        int f = u >> 8, rem = u & 255, lane = rem >> 2, jj = rem & 3;
        int rt = f >> 2, kt = f & 3;
        int row = rt * 16 + (lane & 15);
        int k = kt * 32 + (lane >> 4) * 8 + jj * 2;
        wsu[WS_A1FR + u] = pk2(wA1[row * 128 + k], wA1[row * 128 + k + 1]);
    }
}

// ------------------------------------- K0c: FOLDF + AQK (k-split x8)
__global__ void actor_setup_gemm(
    const float* __restrict__ wQ,  const float* __restrict__ wK,
    const float* __restrict__ wCv, const float* __restrict__ wMo,
    float* __restrict__ ws)
{
    int t = blockIdx.x * 256 + threadIdx.x;   // < 114688
    unsigned* wsu = reinterpret_cast<unsigned*>(ws);
    if (t < 98304) {                       // FOLDF: 12288 outs x 8 slices
        int u = t >> 3, sl = t & 7;
        int f = u >> 8, rem = u & 255, lane = rem >> 2, jj = rem & 3;
        int RT = f / 6, kt = f - RT * 6;
        int row = RT * 16 + (lane & 15);
        int k = kt * 32 + (lane >> 4) * 8 + jj * 2;
        int h = k >> 6, dp = k & 63;
        const float* wmr = wMo + row * 192 + h * 64;
        const float* rhs = (h == 2) ? (ws + WS_WCVV) : wCv;   // WCVV = Wcv@Wv
        float a0 = 0.f, a1 = 0.f;
        #pragma unroll
        for (int i = 0; i < 8; ++i) {
            int d = sl * 8 + i;
            float m = wmr[d];
            a0 = fmaf(m, rhs[d * 64 + dp],     a0);
            a1 = fmaf(m, rhs[d * 64 + dp + 1], a1);
        }
        a0 += __shfl_xor(a0, 1, 64); a0 += __shfl_xor(a0, 2, 64); a0 += __shfl_xor(a0, 4, 64);
        a1 += __shfl_xor(a1, 1, 64); a1 += __shfl_xor(a1, 2, 64); a1 += __shfl_xor(a1, 4, 64);
        if (sl == 0) wsu[WS_FOLDF + u] = pk2(a0, a1);
    } else {                               // AQK: 2048 outs x 8 slices
        int v = t - 98304;
        int u = v >> 3, sl = v & 7;
        int f = u >> 8, rem = u & 255, lane = rem >> 2, jj = rem & 3;
        int qq = lane >> 4, m = lane & 15;
        int dt = f >> 1, kt = f & 1;
        int dp = dt * 16 + m;
        int e = kt * 32 + qq * 8 + jj * 2;
        float a0 = 0.f, a1 = 0.f;
        #pragma unroll
        for (int i = 0; i < 8; ++i) {
            int d = sl * 8 + i;
            float kd = wK[d * 64 + dp];
            a0 = fmaf(wQ[d * 64 + e],     kd, a0);
            a1 = fmaf(wQ[d * 64 + e + 1], kd, a1);
        }
        a0 += __shfl_xor(a0, 1, 64); a0 += __shfl_xor(a0, 2, 64); a0 += __shfl_xor(a0, 4, 64);
        a1 += __shfl_xor(a1, 1, 64); a1 += __shfl_xor(a1, 2, 64); a1 += __shfl_xor(a1, 4, 64);
        if (sl == 0) wsu[WS_AQK + u] = pk2(a0, a1);
    }
}

// -------------------------------- K1: fused pipeline (r12 verbatim)
__global__ __launch_bounds__(256, 3) void actor_mega(
    const float* __restrict__ s0g, const float* __restrict__ s1g,
    const float* __restrict__ s2g,
    const float* __restrict__ bOwn, const float* __restrict__ bEnv,
    const float* __restrict__ bS1g, const float* __restrict__ bS2g,
    const float* __restrict__ bMo,  const float* __restrict__ bA1,
    const float* __restrict__ wA2,  const float* __restrict__ bA2,
    const float* __restrict__ ws,   float* __restrict__ outg)
{
    // X tile: 16 rows x 384B (192 bf16: [0:64 own | 64:128 env | 128:192 P]),
    // XOR-swizzled by (row&7)<<4.
    __shared__ char   xbL[16 * 384];
    __shared__ float  qkL[16][72];          // fp32 qk rows
    __shared__ ushort Hl[4][2][16 * 72];    // per-wave H double-buffer
    __shared__ ushort TR[16 * 72];          // own_e^T staging for qk B-frag
    __shared__ char   mbL[16 * 256];        // mo rows bf16, swizzled
    __shared__ float  aL[16][66];           // a rows fp32

    const int tid  = threadIdx.x;
    const int wid  = tid >> 6;
    const int lane = tid & 63;
    const int q    = lane >> 4;
    const int r    = lane & 15;
    const int swzr = (r & 7) << 4;
    const int eb   = blockIdx.x * 16;
    const f32x4 z = {0.f, 0.f, 0.f, 0.f};

    // ---------------- Phase 1a: own_e (wave wid -> feature tile ht=wid)
    {
        short8 Ao = reinterpret_cast<const short8*>(ws + WS_AOWN)[wid * 64 + lane];
        const float* sp = s0g + (size_t)(eb + r) * 16 + (q & 1) * 8;
        float4 sa = *reinterpret_cast<const float4*>(sp);
        float4 sb = *reinterpret_cast<const float4*>(sp + 4);
        union { short8 s8; unsigned u[4]; } B;
        B.u[0] = pk2(sa.x, sa.y); B.u[1] = pk2(sa.z, sa.w);
        B.u[2] = pk2(sb.x, sb.y); B.u[3] = pk2(sb.z, sb.w);
        f32x4 c = *reinterpret_cast<const f32x4*>(bOwn + wid * 16 + q * 4);
        f32x4 D = __builtin_amdgcn_mfma_f32_16x16x32_bf16(Ao, B.s8, c, 0, 0, 0);
        unsigned p0 = pk2(fmaxf(D[0], 0.f), fmaxf(D[1], 0.f));
        unsigned p1 = pk2(fmaxf(D[2], 0.f), fmaxf(D[3], 0.f));
        *reinterpret_cast<uint2*>(xbL + r * 384 + ((wid * 32 + q * 8) ^ swzr)) =
            make_uint2(p0, p1);
        *reinterpret_cast<uint2*>(reinterpret_cast<char*>(TR) + r * 144 + wid * 32 + q * 8) =
            make_uint2(p0, p1);
    }
    // ---------------- Phase 1b: env_e
    {
        short8 Ae0 = reinterpret_cast<const short8*>(ws + WS_AENV)[(wid * 2 + 0) * 64 + lane];
        short8 Ae1 = reinterpret_cast<const short8*>(ws + WS_AENV)[(wid * 2 + 1) * 64 + lane];
        const float* sb1 = s1g + (size_t)(eb + r) * 64;
        f32x4 D = *reinterpret_cast<const f32x4*>(bEnv + wid * 16 + q * 4);
        {
            float4 sa = *reinterpret_cast<const float4*>(sb1 + q * 8);
            float4 sb = *reinterpret_cast<const float4*>(sb1 + q * 8 + 4);
            union { short8 s8; unsigned u[4]; } B;
            B.u[0] = pk2(sa.x, sa.y); B.u[1] = pk2(sa.z, sa.w);
            B.u[2] = pk2(sb.x, sb.y); B.u[3] = pk2(sb.z, sb.w);
            D = __builtin_amdgcn_mfma_f32_16x16x32_bf16(Ae0, B.s8, D, 0, 0, 0);
        }
        {
            float4 sa = *reinterpret_cast<const float4*>(sb1 + 32 + q * 8);
            float4 sb = *reinterpret_cast<const float4*>(sb1 + 32 + q * 8 + 4);
            union { short8 s8; unsigned u[4]; } B;
            B.u[0] = pk2(sa.x, sa.y); B.u[1] = pk2(sa.z, sa.w);
            B.u[2] = pk2(sb.x, sb.y); B.u[3] = pk2(sb.z, sb.w);
            D = __builtin_amdgcn_mfma_f32_16x16x32_bf16(Ae1, B.s8, D, 0, 0, 0);
        }
        unsigned p0 = pk2(fmaxf(D[0], 0.f), fmaxf(D[1], 0.f));
        unsigned p1 = pk2(fmaxf(D[2], 0.f), fmaxf(D[3], 0.f));
        *reinterpret_cast<uint2*>(xbL + r * 384 + ((128 + wid * 32 + q * 8) ^ swzr)) =
            make_uint2(p0, p1);
    }
    __syncthreads();   // TR complete (all waves' feature tiles)

    // ---------------- Phase 1c: qk = own_e @ wQK (wave wid -> dp tile wid)
    {
        short8 Aq0 = reinterpret_cast<const short8*>(ws + WS_AQK)[(wid * 2 + 0) * 64 + lane];
        short8 Aq1 = reinterpret_cast<const short8*>(ws + WS_AQK)[(wid * 2 + 1) * 64 + lane];
        const char* trb = reinterpret_cast<const char*>(TR) + r * 144;
        short8 B0 = *reinterpret_cast<const short8*>(trb + q * 16);
        short8 B1 = *reinterpret_cast<const short8*>(trb + 64 + q * 16);
        f32x4 D = __builtin_amdgcn_mfma_f32_16x16x32_bf16(Aq0, B0, z, 0, 0, 0);
        D = __builtin_amdgcn_mfma_f32_16x16x32_bf16(Aq1, B1, D, 0, 0, 0);
        *reinterpret_cast<f32x4*>(&qkL[r][wid * 16 + q * 4]) = D;
    }
    __syncthreads();   // qkL complete

    // ---------------- Phase 2: neighbor loop (4 elements x 4 neighbors / wave)
    short8 A1[4], A2[8];
    {
        const short8* p1 = reinterpret_cast<const short8*>(ws + WS_A1F);
        #pragma unroll
        for (int ht = 0; ht < 4; ++ht) A1[ht] = p1[ht * 64 + lane];
        const short8* p2 = reinterpret_cast<const short8*>(ws + WS_A2F);
        #pragma unroll
        for (int f = 0; f < 8; ++f) A2[f] = p2[f * 64 + lane];
    }
    f32x4 b1c[4], b2c[4];
    #pragma unroll
    for (int t4 = 0; t4 < 4; ++t4) {
        b1c[t4] = *reinterpret_cast<const f32x4*>(bS1g + t4 * 16 + q * 4);
        b2c[t4] = *reinterpret_cast<const f32x4*>(bS2g + t4 * 16 + q * 4);
    }
    const int el   = r >> 2;              // local element within wave
    const int j    = r & 3;               // neighbor sub-column
    const int sloc = wid * 4 + el;        // block-local sample 0..15

    float qkf[16];
    #pragma unroll
    for (int dt = 0; dt < 4; ++dt) {
        f32x4 v = *reinterpret_cast<const f32x4*>(&qkL[sloc][dt * 16 + q * 4]);
        qkf[dt*4+0] = v[0]; qkf[dt*4+1] = v[1]; qkf[dt*4+2] = v[2]; qkf[dt*4+3] = v[3];
    }
    const float* s2base = s2g + (size_t)(eb + sloc) * 512 + (q & 1) * 8;

    float den = 0.f;
    f32x4 Pac[4] = {{0,0,0,0},{0,0,0,0},{0,0,0,0},{0,0,0,0}};

    // depth-1 rolling prefetch: 8 floats/lane carried across iterations
    float4 pfa = *reinterpret_cast<const float4*>(s2base + j * 16);
    float4 pfb = *reinterpret_cast<const float4*>(s2base + j * 16 + 4);

    #pragma unroll 2
    for (int it = 0; it < 8; ++it) {
        float4 sa = pfa, sb = pfb;
        if (it < 7) {
            const float* sp = s2base + ((it + 1) * 4 + j) * 16;
            pfa = *reinterpret_cast<const float4*>(sp);
            pfb = *reinterpret_cast<const float4*>(sp + 4);
        }
        union { short8 s8; unsigned u[4]; } B1;
        B1.u[0] = pk2(sa.x, sa.y); B1.u[1] = pk2(sa.z, sa.w);
        B1.u[2] = pk2(sb.x, sb.y); B1.u[3] = pk2(sb.z, sb.w);

        f32x4 hD[4];
        #pragma unroll
        for (int ht = 0; ht < 4; ++ht)
            hD[ht] = __builtin_amdgcn_mfma_f32_16x16x32_bf16(A1[ht], B1.s8, b1c[ht], 0, 0, 0);

        ushort* hrow = &Hl[wid][it & 1][r * 72];
        #pragma unroll
        for (int ht = 0; ht < 4; ++ht) {
            float h0 = fmaxf(hD[ht][0], 0.f), h1 = fmaxf(hD[ht][1], 0.f);
            float h2 = fmaxf(hD[ht][2], 0.f), h3 = fmaxf(hD[ht][3], 0.f);
            *reinterpret_cast<uint2*>(hrow + ht * 16 + q * 4) =
                make_uint2(pk2(h0, h1), pk2(h2, h3));
        }
        short8 B2a = *reinterpret_cast<const short8*>(hrow + q * 8);
        short8 B2b = *reinterpret_cast<const short8*>(hrow + 32 + q * 8);

        f32x4 iD[4];
        #pragma unroll
        for (int dt = 0; dt < 4; ++dt) {
            f32x4 c0 = __builtin_amdgcn_mfma_f32_16x16x32_bf16(A2[dt*2+0], B2a, b2c[dt], 0, 0, 0);
            iD[dt]   = __builtin_amdgcn_mfma_f32_16x16x32_bf16(A2[dt*2+1], B2b, c0, 0, 0, 0);
        }
        float rs = 0.f, sc = 0.f;
        #pragma unroll
        for (int dt = 0; dt < 4; ++dt) {
            #pragma unroll
            for (int i = 0; i < 4; ++i) {
                float x = fmaxf(iD[dt][i], 0.f);
                iD[dt][i] = x;
                rs += x;
                sc = fmaf(x, qkf[dt*4+i], sc);
            }
        }
        sc = rowquad_sum(sc);
        rs = rowquad_sum(rs);
        float w = (rs != 0.f) ? __expf(sc * 0.125f) : 0.f;  // scores O(1e-2)
        den += w;
        #pragma unroll
        for (int dt = 0; dt < 4; ++dt)
            #pragma unroll
            for (int i = 0; i < 4; ++i)
                Pac[dt][i] = fmaf(w, iD[dt][i], Pac[dt][i]);
    }
    #pragma unroll
    for (int m = 1; m <= 2; m <<= 1) {
        den += __shfl_xor(den, m, 64);
        #pragma unroll
        for (int dt = 0; dt < 4; ++dt)
            #pragma unroll
            for (int i = 0; i < 4; ++i)
                Pac[dt][i] += __shfl_xor(Pac[dt][i], m, 64);
    }
    {
        float inv = (den > 0.f) ? (1.f / den) : 0.f;   // all-masked -> P = 0
        if (j == 0) {
            const int swzs = (sloc & 7) << 4;
            #pragma unroll
            for (int dt = 0; dt < 4; ++dt) {
                float p0 = Pac[dt][0] * inv, p1 = Pac[dt][1] * inv;
                float p2 = Pac[dt][2] * inv, p3 = Pac[dt][3] * inv;
                *reinterpret_cast<uint2*>(xbL + sloc * 384 + ((256 + dt * 32 + q * 8) ^ swzs)) =
                    make_uint2(pk2(p0, p1), pk2(p2, p3));
            }
        }
    }
    __syncthreads();   // X tile complete

    // ---------------- Phase 3a: mo = X @ W_fold^T + b_mo
    {
        const short8* fp = reinterpret_cast<const short8*>(ws + WS_FOLDF);
        short8 Amo0[6], Amo1[6];
        #pragma unroll
        for (int kt = 0; kt < 6; ++kt) {
            Amo0[kt] = fp[((wid * 2 + 0) * 6 + kt) * 64 + lane];
            Amo1[kt] = fp[((wid * 2 + 1) * 6 + kt) * 64 + lane];
        }
        short8 Bf[6];
        #pragma unroll
        for (int kt = 0; kt < 6; ++kt)
            Bf[kt] = *reinterpret_cast<const short8*>(
                xbL + r * 384 + ((kt * 64 + q * 16) ^ swzr));
        f32x4 D0 = z, D1 = z;
        #pragma unroll
        for (int kt = 0; kt < 6; ++kt) {
            D0 = __builtin_amdgcn_mfma_f32_16x16x32_bf16(Amo0[kt], Bf[kt], D0, 0, 0, 0);
            D1 = __builtin_amdgcn_mfma_f32_16x16x32_bf16(Amo1[kt], Bf[kt], D1, 0, 0, 0);
        }
        f32x4 bm0 = *reinterpret_cast<const f32x4*>(bMo + wid * 32 + q * 4);
        f32x4 bm1 = *reinterpret_cast<const f32x4*>(bMo + wid * 32 + 16 + q * 4);
        char* wp0 = mbL + r * 256 + ((wid * 64 + q * 8) ^ swzr);
        *reinterpret_cast<unsigned*>(wp0)     = pk2(D0[0] + bm0[0], D0[1] + bm0[1]);
        *reinterpret_cast<unsigned*>(wp0 + 4) = pk2(D0[2] + bm0[2], D0[3] + bm0[3]);
        char* wp1 = mbL + r * 256 + ((wid * 64 + 32 + q * 8) ^ swzr);
        *reinterpret_cast<unsigned*>(wp1)     = pk2(D1[0] + bm1[0], D1[1] + bm1[1]);
        *reinterpret_cast<unsigned*>(wp1 + 4) = pk2(D1[2] + bm1[2], D1[3] + bm1[3]);
    }
    __syncthreads();   // mo tile complete

    // ---------------- Phase 3b: a = relu(mo @ W_a1^T + b_a1)
    {
        const short8* ap = reinterpret_cast<const short8*>(ws + WS_A1FR);
        f32x4 D = z;
        #pragma unroll
        for (int kt = 0; kt < 4; ++kt) {
            short8 Ak = ap[(wid * 4 + kt) * 64 + lane];
            short8 Bk = *reinterpret_cast<const short8*>(
                mbL + r * 256 + ((kt * 64 + q * 16) ^ swzr));
            D = __builtin_amdgcn_mfma_f32_16x16x32_bf16(Ak, Bk, D, 0, 0, 0);
        }
        f32x4 ba = *reinterpret_cast<const f32x4*>(bA1 + wid * 16 + q * 4);
        float a0 = fmaxf(D[0] + ba[0], 0.f), a1v = fmaxf(D[1] + ba[1], 0.f);
        float a2v = fmaxf(D[2] + ba[2], 0.f), a3v = fmaxf(D[3] + ba[3], 0.f);
        *reinterpret_cast<float2*>(&aL[r][wid * 16 + q * 4])     = make_float2(a0, a1v);
        *reinterpret_cast<float2*>(&aL[r][wid * 16 + q * 4 + 2]) = make_float2(a2v, a3v);
    }
    __syncthreads();   // a tile complete

    // ---------------- Phase 3c: out = tanh(a @ W_a2^T + b_a2)
    if (tid < 32) {
        const int s = tid & 15, o = tid >> 4;
        const float* wr = wA2 + o * 64;
        float p = 0.f;
        #pragma unroll
        for (int d = 0; d < 64; ++d) p = fmaf(aL[s][d], wr[d], p);
        outg[(size_t)(eb + s) * 2 + o] = tanhf(p + bA2[o]);
    }
}

extern "C" void kernel_launch(void* const* d_in, const int* in_sizes, int n_in,
                              void* d_out, int out_size, void* d_ws, size_t ws_size,
                              hipStream_t stream) {
    const float* s0   = (const float*)d_in[0];
    const float* s1   = (const float*)d_in[1];
    const float* s2   = (const float*)d_in[2];
    const float* wOwn = (const float*)d_in[3];
    const float* bOwn = (const float*)d_in[4];
    const float* wEnv = (const float*)d_in[5];
    const float* bEnv = (const float*)d_in[6];
    const float* wS1  = (const float*)d_in[7];
    const float* bS1  = (const float*)d_in[8];
    const float* wS2  = (const float*)d_in[9];
    const float* bS2  = (const float*)d_in[10];
    const float* wQ   = (const float*)d_in[11];
    const float* wK   = (const float*)d_in[12];
    const float* wV   = (const float*)d_in[13];
    // d_in[14] (W_cq) / d_in[15] (W_ck): dead code in the reference.
    const float* wCv  = (const float*)d_in[16];
    const float* wMo  = (const float*)d_in[17];
    const float* bMo  = (const float*)d_in[18];
    const float* wA1  = (const float*)d_in[19];
    const float* bA1  = (const float*)d_in[20];
    const float* wA2  = (const float*)d_in[21];
    const float* bA2  = (const float*)d_in[22];
    float* ws  = (float*)d_ws;
    float* out = (float*)d_out;

    hipLaunchKernelGGL(actor_prep1, dim3(168), dim3(256), 0, stream,
                       wCv, wV, wOwn, wEnv, wS1, wS2, wA1, ws);
    hipLaunchKernelGGL(actor_setup_gemm, dim3(448), dim3(256), 0, stream,
                       wQ, wK, wCv, wMo, ws);
    hipLaunchKernelGGL(actor_mega, dim3(16384 / 16), dim3(256), 0, stream,
                       s0, s1, s2, bOwn, bEnv, bS1, bS2, bMo, bA1, wA2, bA2,
                       ws, out);
}